// Round 11
// baseline (549.333 us; speedup 1.0000x reference)
//
#include <hip/hip_runtime.h>
#include <hip/hip_bf16.h>

// Problem constants
#define HEADS 8
#define CH    64
#define HC    512   // HEADS*CH
#define NGR   64
#define NEGS  0.2f
#define BNB   60    // bn_stats blocks

__device__ __forceinline__ float lrelu(float v) {
    return (v > 0.f) ? v : NEGS * v;
}

// bf16 (as ushort) -> fp32
__device__ __forceinline__ float bf2f_lo(unsigned u) { return __uint_as_float(u << 16); }
__device__ __forceinline__ float bf2f_hi(unsigned u) { return __uint_as_float(u & 0xffff0000u); }

// fp32 -> bf16 bits, round-to-nearest-even (finite inputs)
__device__ __forceinline__ unsigned bf16bits(float f) {
    unsigned u = __float_as_uint(f);
    return (u + 0x7fffu + ((u >> 16) & 1u)) >> 16;
}
__device__ __forceinline__ unsigned packbf2(float a, float b) {
    return bf16bits(a) | (bf16bits(b) << 16);
}

// ---------------------------------------------------------------------------
// BN stats stage 1: per-block partial sum/sumsq over 16 features, NO atomics.
__global__ void bn_stats_kernel(const float* __restrict__ x, float* __restrict__ partials,
                                int N, int chunk) {
    int n0 = blockIdx.x * chunk;
    int n1 = min(n0 + chunk, N);
    float s[16], q[16];
#pragma unroll
    for (int i = 0; i < 16; i++) { s[i] = 0.f; q[i] = 0.f; }
    for (int r = n0 + threadIdx.x; r < n1; r += 256) {
        const float4* xr = (const float4*)(x + (size_t)r * 16);
#pragma unroll
        for (int i = 0; i < 4; i++) {
            float4 v = xr[i];
            s[4*i+0] += v.x; q[4*i+0] += v.x * v.x;
            s[4*i+1] += v.y; q[4*i+1] += v.y * v.y;
            s[4*i+2] += v.z; q[4*i+2] += v.z * v.z;
            s[4*i+3] += v.w; q[4*i+3] += v.w * v.w;
        }
    }
#pragma unroll
    for (int k = 0; k < 16; k++) {
#pragma unroll
        for (int off = 32; off; off >>= 1) {
            s[k] += __shfl_down(s[k], off);
            q[k] += __shfl_down(q[k], off);
        }
    }
    __shared__ float lds[4][32];
    int lane = threadIdx.x & 63, wid = threadIdx.x >> 6;
    if (lane == 0) {
#pragma unroll
        for (int k = 0; k < 16; k++) { lds[wid][k] = s[k]; lds[wid][16 + k] = q[k]; }
    }
    __syncthreads();
    int t = threadIdx.x;
    if (t < 32) {
        float v = lds[0][t] + lds[1][t] + lds[2][t] + lds[3][t];
        partials[(size_t)blockIdx.x * 32 + t] = v;
    }
}

// ---------------------------------------------------------------------------
// u/v precompute (blocks 0-2) + BN finalize (block 3) fused into one dispatch.
// uv layout: [0]=u1(16x8) [128]=v1 [256]=u2(64x8) [768]=v2 [1280]=u3 [1792]=v3
__global__ void uv_kernel(const float* __restrict__ W1, const float* __restrict__ a1s,
                          const float* __restrict__ a1d,
                          const float* __restrict__ W2, const float* __restrict__ a2s,
                          const float* __restrict__ a2d,
                          const float* __restrict__ W3, const float* __restrict__ a3s,
                          const float* __restrict__ a3d,
                          float* __restrict__ uv,
                          const float* __restrict__ partials, float* __restrict__ stats,
                          const float* __restrict__ gamma, const float* __restrict__ beta,
                          int N, int nblk) {
    int layer = blockIdx.x;
    int t = threadIdx.x;
    if (layer == 3) {
        __shared__ float sums[32];
        if (t < 32) {
            float v = 0.f;
            for (int b = 0; b < nblk; b++) v += partials[(size_t)b * 32 + t];
            sums[t] = v;
        }
        __syncthreads();
        if (t < 16) {
            float invn = 1.f / (float)N;
            float mean = sums[t] * invn;
            float var  = sums[16 + t] * invn - mean * mean;
            float sc   = gamma[t] * rsqrtf(var + 1e-5f);
            stats[32 + t] = sc;
            stats[48 + t] = beta[t] - mean * sc;
        }
        return;
    }
    const float* W  = (layer == 0) ? W1  : (layer == 1) ? W2  : W3;
    const float* as = (layer == 0) ? a1s : (layer == 1) ? a2s : a3s;
    const float* ad = (layer == 0) ? a1d : (layer == 1) ? a2d : a3d;
    int K = (layer == 0) ? 16 : 64;
    int uofs = (layer == 0) ? 0 : (layer == 1) ? 256 : 1280;
    if (t >= K * 8) return;
    int k = t >> 3, h = t & 7;
    const float* wr = W + (size_t)k * HC + h * CH;
    const float* sr = as + h * CH;
    const float* dr = ad + h * CH;
    float su = 0.f, sv = 0.f;
#pragma unroll 8
    for (int c = 0; c < CH; c++) { su += wr[c] * sr[c]; sv += wr[c] * dr[c]; }
    uv[uofs + k * 8 + h] = su;
    uv[uofs + K * 8 + k * 8 + h] = sv;
}

// ---------------------------------------------------------------------------
// CSR build over dst (edges + self loops). E2 = E + N.
__global__ void count_kernel(const int* __restrict__ ei, int E, int E2,
                             int* __restrict__ counts) {
    int i = blockIdx.x * blockDim.x + threadIdx.x;
    if (i >= E2) return;
    int dst = (i < E) ? ei[E + i] : (i - E);
    atomicAdd(counts + dst, 1);
}

// Single-block scan, 8 elems/thread (2x int4): 4 chunk iterations for N=30000.
__global__ void scan_kernel(const int* __restrict__ counts, int* __restrict__ rowptr,
                            int* __restrict__ cursor, int N) {
    __shared__ int wsum[16];
    __shared__ int base_s;
    int t = threadIdx.x;
    int lane = t & 63, wid = t >> 6;
    if (t == 0) base_s = 0;
    __syncthreads();
    for (int start = 0; start < N; start += 8192) {
        int i0 = start + t * 8;
        int e[8];
#pragma unroll
        for (int i = 0; i < 8; i++) e[i] = 0;
        if (i0 + 7 < N) {
            int4 a = *(const int4*)(counts + i0);
            int4 b = *(const int4*)(counts + i0 + 4);
            e[0] = a.x; e[1] = a.y; e[2] = a.z; e[3] = a.w;
            e[4] = b.x; e[5] = b.y; e[6] = b.z; e[7] = b.w;
        } else {
#pragma unroll
            for (int i = 0; i < 8; i++)
                if (i0 + i < N) e[i] = counts[i0 + i];
        }
        int tot = 0;
#pragma unroll
        for (int i = 0; i < 8; i++) tot += e[i];
        int v = tot;
#pragma unroll
        for (int off = 1; off < 64; off <<= 1) {
            int u = __shfl_up(v, off);
            if (lane >= off) v += u;
        }
        if (lane == 63) wsum[wid] = v;
        __syncthreads();
        if (t < 16) {
            int w = wsum[t];
#pragma unroll
            for (int off = 1; off < 16; off <<= 1) {
                int u = __shfl_up(w, off);
                if (t >= off) w += u;
            }
            wsum[t] = w;
        }
        __syncthreads();
        int run = base_s + (v - tot) + (wid ? wsum[wid - 1] : 0);
        int p[8];
#pragma unroll
        for (int i = 0; i < 8; i++) { p[i] = run; run += e[i]; }
        if (i0 + 7 < N) {
            *(int4*)(rowptr + i0)     = make_int4(p[0], p[1], p[2], p[3]);
            *(int4*)(rowptr + i0 + 4) = make_int4(p[4], p[5], p[6], p[7]);
            *(int4*)(cursor + i0)     = make_int4(p[0], p[1], p[2], p[3]);
            *(int4*)(cursor + i0 + 4) = make_int4(p[4], p[5], p[6], p[7]);
        } else {
#pragma unroll
            for (int i = 0; i < 8; i++)
                if (i0 + i < N) { rowptr[i0 + i] = p[i]; cursor[i0 + i] = p[i]; }
        }
        __syncthreads();
        if (t == 0) base_s += wsum[15];
        __syncthreads();
    }
    if (t == 0) rowptr[N] = base_s;
}

// Scatter edge srcs into CSR order.
__global__ void scatter_kernel(const int* __restrict__ ei, int E, int E2,
                               int* __restrict__ cursor, int* __restrict__ src_csr) {
    int i = blockIdx.x * blockDim.x + threadIdx.x;
    if (i >= E2) return;
    int src, dst;
    if (i < E) { src = ei[i]; dst = ei[E + i]; }
    else       { src = i - E; dst = src; }
    int pos = atomicAdd(cursor + dst, 1);
    src_csr[pos] = src;
}

// ---------------------------------------------------------------------------
// GEMM v3: h[N,512](bf16) = xin[N,K](fp32) @ W[K,512]. Register-blocked
// 16 rows x 4 cols/thread, k-step 4 via b128 LDS reads. asv/adv epilogue.
template <int K>
__launch_bounds__(256, 2)
__global__ void gemm_kernel(const float* __restrict__ xin, const float* __restrict__ W,
                            unsigned* __restrict__ hout, int N,
                            const float* __restrict__ scale, const float* __restrict__ shift,
                            const float* __restrict__ u, const float* __restrict__ v,
                            float* __restrict__ asv, float* __restrict__ adv) {
    const int BM = 32;
    __shared__ float xs[BM * K];
    __shared__ float us[K * 8];
    __shared__ float vs[K * 8];
    int row0 = blockIdx.x * BM;
    int t = threadIdx.x;
    for (int idx = t; idx < K * 8; idx += 256) { us[idx] = u[idx]; vs[idx] = v[idx]; }
    for (int idx = t; idx < BM * K; idx += 256) {
        int r = row0 + idx / K;
        int f = idx & (K - 1);
        float vv = (r < N) ? xin[(size_t)r * K + f] : 0.f;
        if (scale) vv = vv * scale[f] + shift[f];
        xs[idx] = vv;
    }
    __syncthreads();
    int c4 = 4 * (t & 127);
    int r0 = 16 * (t >> 7);
    float4 acc[16];
#pragma unroll
    for (int r = 0; r < 16; r++) acc[r] = make_float4(0.f, 0.f, 0.f, 0.f);
    for (int k0 = 0; k0 < K; k0 += 4) {
        float4 w0 = *(const float4*)(W + (size_t)(k0 + 0) * HC + c4);
        float4 w1 = *(const float4*)(W + (size_t)(k0 + 1) * HC + c4);
        float4 w2 = *(const float4*)(W + (size_t)(k0 + 2) * HC + c4);
        float4 w3 = *(const float4*)(W + (size_t)(k0 + 3) * HC + c4);
#pragma unroll
        for (int r = 0; r < 16; r++) {
            float4 xv = *(const float4*)(xs + (r0 + r) * K + k0);
            acc[r].x += xv.x * w0.x + xv.y * w1.x + xv.z * w2.x + xv.w * w3.x;
            acc[r].y += xv.x * w0.y + xv.y * w1.y + xv.z * w2.y + xv.w * w3.y;
            acc[r].z += xv.x * w0.z + xv.y * w1.z + xv.z * w2.z + xv.w * w3.z;
            acc[r].w += xv.x * w0.w + xv.y * w1.w + xv.z * w2.w + xv.w * w3.w;
        }
    }
#pragma unroll
    for (int r = 0; r < 16; r++) {
        int rr = row0 + r0 + r;
        if (rr < N) {
            uint2 d;
            d.x = packbf2(acc[r].x, acc[r].y);
            d.y = packbf2(acc[r].z, acc[r].w);
            *(uint2*)(hout + (size_t)rr * (HC / 2) + 2 * (t & 127)) = d;
        }
    }
    {
        int r = t >> 3, hh = t & 7;
        int rr = row0 + r;
        if (rr < N) {
            float su = 0.f, sv = 0.f;
            for (int k = 0; k < K; k++) {
                float xv = xs[r * K + k];
                su += xv * us[k * 8 + hh];
                sv += xv * vs[k * 8 + hh];
            }
            asv[(size_t)rr * 8 + hh] = su;
            adv[(size_t)rr * 8 + hh] = sv;
        }
    }
}

// ---------------------------------------------------------------------------
// Fused softmax+aggregation: one WAVE per dst node, 8-edge unroll for MLP
// (8 outstanding uint4 gathers per lane). w computed inline.
__global__ void agg_kernel(const int* __restrict__ rp, const int* __restrict__ src_csr,
                           const float* __restrict__ asv, const float* __restrict__ adv,
                           const ushort* __restrict__ hbuf, const float* __restrict__ bias,
                           float* __restrict__ xout, int N, int dorelu) {
    int gw = (blockIdx.x * blockDim.x + threadIdx.x) >> 6;  // node id
    int lane = threadIdx.x & 63;
    if (gw >= N) return;
    int head = lane >> 3;
    size_t lofs = 8 * (size_t)lane;
    int jb = rp[gw], je = rp[gw + 1];
    float ad = adv[(size_t)gw * 8 + head];
    float acc[8];
#pragma unroll
    for (int r = 0; r < 8; r++) acc[r] = 0.f;
    float den = 0.f;
    int j = jb;
    for (; j + 8 <= je; j += 8) {
        int s[8];
        float w[8];
        uint4 pk[8];
#pragma unroll
        for (int i = 0; i < 8; i++) s[i] = src_csr[j + i];
#pragma unroll
        for (int i = 0; i < 8; i++) pk[i] = *(const uint4*)(hbuf + (size_t)s[i] * HC + lofs);
#pragma unroll
        for (int i = 0; i < 8; i++) w[i] = __expf(lrelu(asv[(size_t)s[i] * 8 + head] + ad));
#pragma unroll
        for (int i = 0; i < 8; i++) {
            den += w[i];
            acc[0] += w[i] * bf2f_lo(pk[i].x); acc[1] += w[i] * bf2f_hi(pk[i].x);
            acc[2] += w[i] * bf2f_lo(pk[i].y); acc[3] += w[i] * bf2f_hi(pk[i].y);
            acc[4] += w[i] * bf2f_lo(pk[i].z); acc[5] += w[i] * bf2f_hi(pk[i].z);
            acc[6] += w[i] * bf2f_lo(pk[i].w); acc[7] += w[i] * bf2f_hi(pk[i].w);
        }
    }
    for (; j + 4 <= je; j += 4) {
        int s[4];
        float w[4];
        uint4 pk[4];
#pragma unroll
        for (int i = 0; i < 4; i++) s[i] = src_csr[j + i];
#pragma unroll
        for (int i = 0; i < 4; i++) pk[i] = *(const uint4*)(hbuf + (size_t)s[i] * HC + lofs);
#pragma unroll
        for (int i = 0; i < 4; i++) w[i] = __expf(lrelu(asv[(size_t)s[i] * 8 + head] + ad));
#pragma unroll
        for (int i = 0; i < 4; i++) {
            den += w[i];
            acc[0] += w[i] * bf2f_lo(pk[i].x); acc[1] += w[i] * bf2f_hi(pk[i].x);
            acc[2] += w[i] * bf2f_lo(pk[i].y); acc[3] += w[i] * bf2f_hi(pk[i].y);
            acc[4] += w[i] * bf2f_lo(pk[i].z); acc[5] += w[i] * bf2f_hi(pk[i].z);
            acc[6] += w[i] * bf2f_lo(pk[i].w); acc[7] += w[i] * bf2f_hi(pk[i].w);
        }
    }
    for (; j < je; j++) {
        int s0 = src_csr[j];
        float w0 = __expf(lrelu(asv[(size_t)s0 * 8 + head] + ad));
        uint4 p0 = *(const uint4*)(hbuf + (size_t)s0 * HC + lofs);
        den += w0;
        acc[0] += w0 * bf2f_lo(p0.x); acc[1] += w0 * bf2f_hi(p0.x);
        acc[2] += w0 * bf2f_lo(p0.y); acc[3] += w0 * bf2f_hi(p0.y);
        acc[4] += w0 * bf2f_lo(p0.z); acc[5] += w0 * bf2f_hi(p0.z);
        acc[6] += w0 * bf2f_lo(p0.w); acc[7] += w0 * bf2f_hi(p0.w);
    }
    float inv = 1.f / (den + 1e-16f);
#pragma unroll
    for (int r = 0; r < 8; r++) {
        acc[r] *= inv;
        acc[r] += __shfl_xor(acc[r], 8);
        acc[r] += __shfl_xor(acc[r], 16);
        acc[r] += __shfl_xor(acc[r], 32);
    }
    if (lane < 8) {
        const float4* b4 = (const float4*)(bias + 8 * lane);
        float4 bv0 = b4[0], bv1 = b4[1];
        float4 o0, o1;
        o0.x = acc[0] * 0.125f + bv0.x;
        o0.y = acc[1] * 0.125f + bv0.y;
        o0.z = acc[2] * 0.125f + bv0.z;
        o0.w = acc[3] * 0.125f + bv0.w;
        o1.x = acc[4] * 0.125f + bv1.x;
        o1.y = acc[5] * 0.125f + bv1.y;
        o1.z = acc[6] * 0.125f + bv1.z;
        o1.w = acc[7] * 0.125f + bv1.w;
        if (dorelu) {
            o0.x = fmaxf(o0.x, 0.f); o0.y = fmaxf(o0.y, 0.f);
            o0.z = fmaxf(o0.z, 0.f); o0.w = fmaxf(o0.w, 0.f);
            o1.x = fmaxf(o1.x, 0.f); o1.y = fmaxf(o1.y, 0.f);
            o1.z = fmaxf(o1.z, 0.f); o1.w = fmaxf(o1.w, 0.f);
        }
        float4* op = (float4*)(xout + (size_t)gw * CH + 8 * lane);
        op[0] = o0;
        op[1] = o1;
    }
}

// ---------------------------------------------------------------------------
// Fused mean-pool + linear: one block per graph (batch sorted, binary search).
__global__ void poolfinal_kernel(const float* __restrict__ x, const int* __restrict__ batch,
                                 const float* __restrict__ linW, const float* __restrict__ linb,
                                 float* __restrict__ out, int N) {
    int g = blockIdx.x;
    int lo = 0, hi = N;
    while (lo < hi) { int m = (lo + hi) >> 1; if (batch[m] < g) lo = m + 1; else hi = m; }
    int lo2 = lo, hi2 = N;
    while (lo2 < hi2) { int m = (lo2 + hi2) >> 1; if (batch[m] < g + 1) lo2 = m + 1; else hi2 = m; }
    int n0 = lo, n1 = lo2;
    int c  = threadIdx.x & 63;
    int nl = threadIdx.x >> 6;
    float acc = 0.f;
    for (int n = n0 + nl; n < n1; n += 4)
        acc += x[(size_t)n * CH + c];
    __shared__ float lds[4][64];
    lds[nl][c] = acc;
    __syncthreads();
    __shared__ float pooled[64];
    if (threadIdx.x < 64) {
        float cnt = (float)max(n1 - n0, 1);
        pooled[threadIdx.x] = (lds[0][threadIdx.x] + lds[1][threadIdx.x] +
                               lds[2][threadIdx.x] + lds[3][threadIdx.x]) / cnt;
    }
    __syncthreads();
    if (threadIdx.x < 2) {
        int k = threadIdx.x;
        float s = 0.f;
#pragma unroll
        for (int cc = 0; cc < CH; cc++) s += pooled[cc] * linW[cc * 2 + k];
        out[g * 2 + k] = s + linb[k];
    }
}

// ---------------------------------------------------------------------------
extern "C" void kernel_launch(void* const* d_in, const int* in_sizes, int n_in,
                              void* d_out, int out_size, void* d_ws, size_t ws_size,
                              hipStream_t stream) {
    const float* x      = (const float*)d_in[0];
    const int*   ei     = (const int*)d_in[1];
    const int*   batch  = (const int*)d_in[3];
    const float* gamma  = (const float*)d_in[4];
    const float* beta   = (const float*)d_in[5];
    const float* W1     = (const float*)d_in[6];
    const float* a1s    = (const float*)d_in[7];
    const float* a1d    = (const float*)d_in[8];
    const float* b1     = (const float*)d_in[9];
    const float* W2     = (const float*)d_in[10];
    const float* a2s    = (const float*)d_in[11];
    const float* a2d    = (const float*)d_in[12];
    const float* b2     = (const float*)d_in[13];
    const float* W3     = (const float*)d_in[14];
    const float* a3s    = (const float*)d_in[15];
    const float* a3d    = (const float*)d_in[16];
    const float* b3     = (const float*)d_in[17];
    const float* linW   = (const float*)d_in[18];
    const float* linb   = (const float*)d_in[19];
    float* out = (float*)d_out;

    const int N  = in_sizes[0] / 16;
    const int E  = in_sizes[1] / 2;
    const int E2 = E + N;

    // Workspace layout (256B aligned slices)
    char* p = (char*)d_ws;
    size_t off = 0;
    auto alloc = [&](size_t bytes) {
        void* r = p + off;
        off += (bytes + 255) & ~(size_t)255;
        return r;
    };
    unsigned* hbuf   = (unsigned*)alloc((size_t)N * HC * 2);   // bf16 x2 packed
    float* xa        = (float*)alloc((size_t)N * CH * 4);
    float* xb        = (float*)alloc((size_t)N * CH * 4);
    float* asv       = (float*)alloc((size_t)N * HEADS * 4);
    float* adv       = (float*)alloc((size_t)N * HEADS * 4);
    float* stats     = (float*)alloc(64 * 4);
    float* partials  = (float*)alloc((size_t)BNB * 32 * 4);
    float* uv        = (float*)alloc(2304 * 4);
    int*   rowptr    = (int*)alloc((size_t)(N + 1) * 4);
    int*   cursor    = (int*)alloc((size_t)N * 4);
    int*   counts    = (int*)alloc((size_t)N * 4);
    int*   src_csr   = (int*)alloc((size_t)E2 * 4);
    (void)ws_size;

    const int TB = 256;
    int gE2 = (E2 + TB - 1) / TB;
    int gGm = (N + 31) / 32;               // BM=32
    int gWv = (N * 64 + TB - 1) / TB;      // one wave per node
    int bnChunk = (N + BNB - 1) / BNB;

    const ushort* hb = (const ushort*)hbuf;

    // zero-init accumulators
    hipMemsetAsync(counts, 0, (size_t)N * 4, stream);

    // BN stats, then fused (uv precompute + BN finalize)
    bn_stats_kernel<<<BNB, TB, 0, stream>>>(x, partials, N, bnChunk);
    uv_kernel<<<4, 512, 0, stream>>>(W1, a1s, a1d, W2, a2s, a2d, W3, a3s, a3d, uv,
                                     partials, stats, gamma, beta, N, BNB);

    // CSR over dst
    count_kernel<<<gE2, TB, 0, stream>>>(ei, E, E2, counts);
    scan_kernel<<<1, 1024, 0, stream>>>(counts, rowptr, cursor, N);
    scatter_kernel<<<gE2, TB, 0, stream>>>(ei, E, E2, cursor, src_csr);

    // ---- Layer 1 (BN fused into GEMM staging; asv/adv fused epilogue) ----
    gemm_kernel<16><<<gGm, TB, 0, stream>>>(x, W1, hbuf, N, stats + 32, stats + 48,
                                            uv + 0, uv + 128, asv, adv);
    agg_kernel<<<gWv, TB, 0, stream>>>(rowptr, src_csr, asv, adv, hb, b1, xa, N, 1);

    // ---- Layer 2 ----
    gemm_kernel<64><<<gGm, TB, 0, stream>>>(xa, W2, hbuf, N, nullptr, nullptr,
                                            uv + 256, uv + 768, asv, adv);
    agg_kernel<<<gWv, TB, 0, stream>>>(rowptr, src_csr, asv, adv, hb, b2, xb, N, 1);

    // ---- Layer 3 ----
    gemm_kernel<64><<<gGm, TB, 0, stream>>>(xb, W3, hbuf, N, nullptr, nullptr,
                                            uv + 1280, uv + 1792, asv, adv);
    agg_kernel<<<gWv, TB, 0, stream>>>(rowptr, src_csr, asv, adv, hb, b3, xa, N, 0);

    // ---- Fused mean-pool + linear ----
    poolfinal_kernel<<<NGR, TB, 0, stream>>>(xa, batch, linW, linb, out, N);
}

// Round 12
// 533.345 us; speedup vs baseline: 1.0300x; 1.0300x over previous
//
#include <hip/hip_runtime.h>
#include <hip/hip_bf16.h>

// Problem constants
#define HEADS 8
#define CH    64
#define HC    512   // HEADS*CH
#define NGR   64
#define NEGS  0.2f
#define BNB   60    // bn_stats blocks

__device__ __forceinline__ float lrelu(float v) {
    return (v > 0.f) ? v : NEGS * v;
}

// bf16 (as ushort) -> fp32
__device__ __forceinline__ float bf2f_lo(unsigned u) { return __uint_as_float(u << 16); }
__device__ __forceinline__ float bf2f_hi(unsigned u) { return __uint_as_float(u & 0xffff0000u); }

// fp32 -> bf16 bits, round-to-nearest-even (finite inputs)
__device__ __forceinline__ unsigned bf16bits(float f) {
    unsigned u = __float_as_uint(f);
    return (u + 0x7fffu + ((u >> 16) & 1u)) >> 16;
}
__device__ __forceinline__ unsigned packbf2(float a, float b) {
    return bf16bits(a) | (bf16bits(b) << 16);
}

// ---------------------------------------------------------------------------
// D1: blocks [0,BNB) = BN stats partials; blocks [BNB,..) = CSR count.
// Independent work merged into one dispatch (overlap BW-bound with atomics).
__global__ void stats_count_kernel(const float* __restrict__ x, float* __restrict__ partials,
                                   int N, int chunk,
                                   const int* __restrict__ ei, int E, int E2,
                                   int* __restrict__ counts) {
    if (blockIdx.x >= BNB) {
        int i = (blockIdx.x - BNB) * blockDim.x + threadIdx.x;
        if (i < E2) {
            int dst = (i < E) ? ei[E + i] : (i - E);
            atomicAdd(counts + dst, 1);
        }
        return;
    }
    int n0 = blockIdx.x * chunk;
    int n1 = min(n0 + chunk, N);
    float s[16], q[16];
#pragma unroll
    for (int i = 0; i < 16; i++) { s[i] = 0.f; q[i] = 0.f; }
    for (int r = n0 + threadIdx.x; r < n1; r += 256) {
        const float4* xr = (const float4*)(x + (size_t)r * 16);
#pragma unroll
        for (int i = 0; i < 4; i++) {
            float4 v = xr[i];
            s[4*i+0] += v.x; q[4*i+0] += v.x * v.x;
            s[4*i+1] += v.y; q[4*i+1] += v.y * v.y;
            s[4*i+2] += v.z; q[4*i+2] += v.z * v.z;
            s[4*i+3] += v.w; q[4*i+3] += v.w * v.w;
        }
    }
#pragma unroll
    for (int k = 0; k < 16; k++) {
#pragma unroll
        for (int off = 32; off; off >>= 1) {
            s[k] += __shfl_down(s[k], off);
            q[k] += __shfl_down(q[k], off);
        }
    }
    __shared__ float lds[4][32];
    int lane = threadIdx.x & 63, wid = threadIdx.x >> 6;
    if (lane == 0) {
#pragma unroll
        for (int k = 0; k < 16; k++) { lds[wid][k] = s[k]; lds[wid][16 + k] = q[k]; }
    }
    __syncthreads();
    int t = threadIdx.x;
    if (t < 32) {
        float v = lds[0][t] + lds[1][t] + lds[2][t] + lds[3][t];
        partials[(size_t)blockIdx.x * 32 + t] = v;
    }
}

// ---------------------------------------------------------------------------
// D2: blocks 0-2 = u/v precompute; block 3 = BN finalize; block 4 = CSR scan.
// uv layout: [0]=u1(16x8) [128]=v1 [256]=u2(64x8) [768]=v2 [1280]=u3 [1792]=v3
__global__ void uv_scan_kernel(const float* __restrict__ W1, const float* __restrict__ a1s,
                               const float* __restrict__ a1d,
                               const float* __restrict__ W2, const float* __restrict__ a2s,
                               const float* __restrict__ a2d,
                               const float* __restrict__ W3, const float* __restrict__ a3s,
                               const float* __restrict__ a3d,
                               float* __restrict__ uv,
                               const float* __restrict__ partials, float* __restrict__ stats,
                               const float* __restrict__ gamma, const float* __restrict__ beta,
                               int N, int nblk,
                               const int* __restrict__ counts, int* __restrict__ rowptr,
                               int* __restrict__ cursor) {
    int role = blockIdx.x;
    int t = threadIdx.x;
    if (role == 3) {
        // BN finalize: stats[32..47]=scale, stats[48..63]=shift.
        __shared__ float sums[32];
        if (t < 32) {
            float v = 0.f;
            for (int b = 0; b < nblk; b++) v += partials[(size_t)b * 32 + t];
            sums[t] = v;
        }
        __syncthreads();
        if (t < 16) {
            float invn = 1.f / (float)N;
            float mean = sums[t] * invn;
            float var  = sums[16 + t] * invn - mean * mean;
            float sc   = gamma[t] * rsqrtf(var + 1e-5f);
            stats[32 + t] = sc;
            stats[48 + t] = beta[t] - mean * sc;
        }
        return;
    }
    if (role == 4) {
        // Single-block scan, 8 elems/thread (2x int4), 1024 threads.
        __shared__ int wsum[16];
        __shared__ int base_s;
        int lane = t & 63, wid = t >> 6;
        if (t == 0) base_s = 0;
        __syncthreads();
        for (int start = 0; start < N; start += 8192) {
            int i0 = start + t * 8;
            int e[8];
#pragma unroll
            for (int i = 0; i < 8; i++) e[i] = 0;
            if (i0 + 7 < N) {
                int4 a = *(const int4*)(counts + i0);
                int4 b = *(const int4*)(counts + i0 + 4);
                e[0] = a.x; e[1] = a.y; e[2] = a.z; e[3] = a.w;
                e[4] = b.x; e[5] = b.y; e[6] = b.z; e[7] = b.w;
            } else {
#pragma unroll
                for (int i = 0; i < 8; i++)
                    if (i0 + i < N) e[i] = counts[i0 + i];
            }
            int tot = 0;
#pragma unroll
            for (int i = 0; i < 8; i++) tot += e[i];
            int v = tot;
#pragma unroll
            for (int off = 1; off < 64; off <<= 1) {
                int u = __shfl_up(v, off);
                if (lane >= off) v += u;
            }
            if (lane == 63) wsum[wid] = v;
            __syncthreads();
            if (t < 16) {
                int w = wsum[t];
#pragma unroll
                for (int off = 1; off < 16; off <<= 1) {
                    int u = __shfl_up(w, off);
                    if (t >= off) w += u;
                }
                wsum[t] = w;
            }
            __syncthreads();
            int run = base_s + (v - tot) + (wid ? wsum[wid - 1] : 0);
            int p[8];
#pragma unroll
            for (int i = 0; i < 8; i++) { p[i] = run; run += e[i]; }
            if (i0 + 7 < N) {
                *(int4*)(rowptr + i0)     = make_int4(p[0], p[1], p[2], p[3]);
                *(int4*)(rowptr + i0 + 4) = make_int4(p[4], p[5], p[6], p[7]);
                *(int4*)(cursor + i0)     = make_int4(p[0], p[1], p[2], p[3]);
                *(int4*)(cursor + i0 + 4) = make_int4(p[4], p[5], p[6], p[7]);
            } else {
#pragma unroll
                for (int i = 0; i < 8; i++)
                    if (i0 + i < N) { rowptr[i0 + i] = p[i]; cursor[i0 + i] = p[i]; }
            }
            __syncthreads();
            if (t == 0) base_s += wsum[15];
            __syncthreads();
        }
        if (t == 0) rowptr[N] = base_s;
        return;
    }
    // roles 0-2: uv for layer `role`
    const float* W  = (role == 0) ? W1  : (role == 1) ? W2  : W3;
    const float* as = (role == 0) ? a1s : (role == 1) ? a2s : a3s;
    const float* ad = (role == 0) ? a1d : (role == 1) ? a2d : a3d;
    int K = (role == 0) ? 16 : 64;
    int uofs = (role == 0) ? 0 : (role == 1) ? 256 : 1280;
    if (t >= K * 8) return;
    int k = t >> 3, h = t & 7;
    const float* wr = W + (size_t)k * HC + h * CH;
    const float* sr = as + h * CH;
    const float* dr = ad + h * CH;
    float su = 0.f, sv = 0.f;
#pragma unroll 8
    for (int c = 0; c < CH; c++) { su += wr[c] * sr[c]; sv += wr[c] * dr[c]; }
    uv[uofs + k * 8 + h] = su;
    uv[uofs + K * 8 + k * 8 + h] = sv;
}

// ---------------------------------------------------------------------------
// Scatter edge srcs into CSR order.
__global__ void scatter_kernel(const int* __restrict__ ei, int E, int E2,
                               int* __restrict__ cursor, int* __restrict__ src_csr) {
    int i = blockIdx.x * blockDim.x + threadIdx.x;
    if (i >= E2) return;
    int src, dst;
    if (i < E) { src = ei[i]; dst = ei[E + i]; }
    else       { src = i - E; dst = src; }
    int pos = atomicAdd(cursor + dst, 1);
    src_csr[pos] = src;
}

// ---------------------------------------------------------------------------
// GEMM v3: h[N,512](bf16) = xin[N,K](fp32) @ W[K,512]. Register-blocked
// 16 rows x 4 cols/thread, k-step 4 via b128 LDS reads. asv/adv epilogue.
template <int K>
__launch_bounds__(256, 2)
__global__ void gemm_kernel(const float* __restrict__ xin, const float* __restrict__ W,
                            unsigned* __restrict__ hout, int N,
                            const float* __restrict__ scale, const float* __restrict__ shift,
                            const float* __restrict__ u, const float* __restrict__ v,
                            float* __restrict__ asv, float* __restrict__ adv) {
    const int BM = 32;
    __shared__ float xs[BM * K];
    __shared__ float us[K * 8];
    __shared__ float vs[K * 8];
    int row0 = blockIdx.x * BM;
    int t = threadIdx.x;
    for (int idx = t; idx < K * 8; idx += 256) { us[idx] = u[idx]; vs[idx] = v[idx]; }
    for (int idx = t; idx < BM * K; idx += 256) {
        int r = row0 + idx / K;
        int f = idx & (K - 1);
        float vv = (r < N) ? xin[(size_t)r * K + f] : 0.f;
        if (scale) vv = vv * scale[f] + shift[f];
        xs[idx] = vv;
    }
    __syncthreads();
    int c4 = 4 * (t & 127);
    int r0 = 16 * (t >> 7);
    float4 acc[16];
#pragma unroll
    for (int r = 0; r < 16; r++) acc[r] = make_float4(0.f, 0.f, 0.f, 0.f);
    for (int k0 = 0; k0 < K; k0 += 4) {
        float4 w0 = *(const float4*)(W + (size_t)(k0 + 0) * HC + c4);
        float4 w1 = *(const float4*)(W + (size_t)(k0 + 1) * HC + c4);
        float4 w2 = *(const float4*)(W + (size_t)(k0 + 2) * HC + c4);
        float4 w3 = *(const float4*)(W + (size_t)(k0 + 3) * HC + c4);
#pragma unroll
        for (int r = 0; r < 16; r++) {
            float4 xv = *(const float4*)(xs + (r0 + r) * K + k0);
            acc[r].x += xv.x * w0.x + xv.y * w1.x + xv.z * w2.x + xv.w * w3.x;
            acc[r].y += xv.x * w0.y + xv.y * w1.y + xv.z * w2.y + xv.w * w3.y;
            acc[r].z += xv.x * w0.z + xv.y * w1.z + xv.z * w2.z + xv.w * w3.z;
            acc[r].w += xv.x * w0.w + xv.y * w1.w + xv.z * w2.w + xv.w * w3.w;
        }
    }
#pragma unroll
    for (int r = 0; r < 16; r++) {
        int rr = row0 + r0 + r;
        if (rr < N) {
            uint2 d;
            d.x = packbf2(acc[r].x, acc[r].y);
            d.y = packbf2(acc[r].z, acc[r].w);
            *(uint2*)(hout + (size_t)rr * (HC / 2) + 2 * (t & 127)) = d;
        }
    }
    {
        int r = t >> 3, hh = t & 7;
        int rr = row0 + r;
        if (rr < N) {
            float su = 0.f, sv = 0.f;
            for (int k = 0; k < K; k++) {
                float xv = xs[r * K + k];
                su += xv * us[k * 8 + hh];
                sv += xv * vs[k * 8 + hh];
            }
            asv[(size_t)rr * 8 + hh] = su;
            adv[(size_t)rr * 8 + hh] = sv;
        }
    }
}

// ---------------------------------------------------------------------------
// Fused softmax+aggregation: one WAVE per dst node, 4-edge unroll (VGPR 32,
// occ ~68% — measured equal to 8-unroll; plateau is L2 request rate).
__global__ void agg_kernel(const int* __restrict__ rp, const int* __restrict__ src_csr,
                           const float* __restrict__ asv, const float* __restrict__ adv,
                           const ushort* __restrict__ hbuf, const float* __restrict__ bias,
                           float* __restrict__ xout, int N, int dorelu) {
    int gw = (blockIdx.x * blockDim.x + threadIdx.x) >> 6;  // node id
    int lane = threadIdx.x & 63;
    if (gw >= N) return;
    int head = lane >> 3;
    size_t lofs = 8 * (size_t)lane;
    int jb = rp[gw], je = rp[gw + 1];
    float ad = adv[(size_t)gw * 8 + head];
    float acc[8];
#pragma unroll
    for (int r = 0; r < 8; r++) acc[r] = 0.f;
    float den = 0.f;
    int j = jb;
    for (; j + 4 <= je; j += 4) {
        int s0 = src_csr[j],     s1 = src_csr[j + 1];
        int s2 = src_csr[j + 2], s3 = src_csr[j + 3];
        float w0 = __expf(lrelu(asv[(size_t)s0 * 8 + head] + ad));
        float w1 = __expf(lrelu(asv[(size_t)s1 * 8 + head] + ad));
        float w2 = __expf(lrelu(asv[(size_t)s2 * 8 + head] + ad));
        float w3 = __expf(lrelu(asv[(size_t)s3 * 8 + head] + ad));
        uint4 p0 = *(const uint4*)(hbuf + (size_t)s0 * HC + lofs);
        uint4 p1 = *(const uint4*)(hbuf + (size_t)s1 * HC + lofs);
        uint4 p2 = *(const uint4*)(hbuf + (size_t)s2 * HC + lofs);
        uint4 p3 = *(const uint4*)(hbuf + (size_t)s3 * HC + lofs);
        den += (w0 + w1) + (w2 + w3);
        acc[0] += w0 * bf2f_lo(p0.x); acc[1] += w0 * bf2f_hi(p0.x);
        acc[2] += w0 * bf2f_lo(p0.y); acc[3] += w0 * bf2f_hi(p0.y);
        acc[4] += w0 * bf2f_lo(p0.z); acc[5] += w0 * bf2f_hi(p0.z);
        acc[6] += w0 * bf2f_lo(p0.w); acc[7] += w0 * bf2f_hi(p0.w);
        acc[0] += w1 * bf2f_lo(p1.x); acc[1] += w1 * bf2f_hi(p1.x);
        acc[2] += w1 * bf2f_lo(p1.y); acc[3] += w1 * bf2f_hi(p1.y);
        acc[4] += w1 * bf2f_lo(p1.z); acc[5] += w1 * bf2f_hi(p1.z);
        acc[6] += w1 * bf2f_lo(p1.w); acc[7] += w1 * bf2f_hi(p1.w);
        acc[0] += w2 * bf2f_lo(p2.x); acc[1] += w2 * bf2f_hi(p2.x);
        acc[2] += w2 * bf2f_lo(p2.y); acc[3] += w2 * bf2f_hi(p2.y);
        acc[4] += w2 * bf2f_lo(p2.z); acc[5] += w2 * bf2f_hi(p2.z);
        acc[6] += w2 * bf2f_lo(p2.w); acc[7] += w2 * bf2f_hi(p2.w);
        acc[0] += w3 * bf2f_lo(p3.x); acc[1] += w3 * bf2f_hi(p3.x);
        acc[2] += w3 * bf2f_lo(p3.y); acc[3] += w3 * bf2f_hi(p3.y);
        acc[4] += w3 * bf2f_lo(p3.z); acc[5] += w3 * bf2f_hi(p3.z);
        acc[6] += w3 * bf2f_lo(p3.w); acc[7] += w3 * bf2f_hi(p3.w);
    }
    for (; j < je; j++) {
        int s0 = src_csr[j];
        float w0 = __expf(lrelu(asv[(size_t)s0 * 8 + head] + ad));
        uint4 p0 = *(const uint4*)(hbuf + (size_t)s0 * HC + lofs);
        den += w0;
        acc[0] += w0 * bf2f_lo(p0.x); acc[1] += w0 * bf2f_hi(p0.x);
        acc[2] += w0 * bf2f_lo(p0.y); acc[3] += w0 * bf2f_hi(p0.y);
        acc[4] += w0 * bf2f_lo(p0.z); acc[5] += w0 * bf2f_hi(p0.z);
        acc[6] += w0 * bf2f_lo(p0.w); acc[7] += w0 * bf2f_hi(p0.w);
    }
    float inv = 1.f / (den + 1e-16f);
#pragma unroll
    for (int r = 0; r < 8; r++) {
        acc[r] *= inv;
        acc[r] += __shfl_xor(acc[r], 8);
        acc[r] += __shfl_xor(acc[r], 16);
        acc[r] += __shfl_xor(acc[r], 32);
    }
    if (lane < 8) {
        const float4* b4 = (const float4*)(bias + 8 * lane);
        float4 bv0 = b4[0], bv1 = b4[1];
        float4 o0, o1;
        o0.x = acc[0] * 0.125f + bv0.x;
        o0.y = acc[1] * 0.125f + bv0.y;
        o0.z = acc[2] * 0.125f + bv0.z;
        o0.w = acc[3] * 0.125f + bv0.w;
        o1.x = acc[4] * 0.125f + bv1.x;
        o1.y = acc[5] * 0.125f + bv1.y;
        o1.z = acc[6] * 0.125f + bv1.z;
        o1.w = acc[7] * 0.125f + bv1.w;
        if (dorelu) {
            o0.x = fmaxf(o0.x, 0.f); o0.y = fmaxf(o0.y, 0.f);
            o0.z = fmaxf(o0.z, 0.f); o0.w = fmaxf(o0.w, 0.f);
            o1.x = fmaxf(o1.x, 0.f); o1.y = fmaxf(o1.y, 0.f);
            o1.z = fmaxf(o1.z, 0.f); o1.w = fmaxf(o1.w, 0.f);
        }
        float4* op = (float4*)(xout + (size_t)gw * CH + 8 * lane);
        op[0] = o0;
        op[1] = o1;
    }
}

// ---------------------------------------------------------------------------
// Fused mean-pool + linear: one block per graph (batch sorted, binary search).
__global__ void poolfinal_kernel(const float* __restrict__ x, const int* __restrict__ batch,
                                 const float* __restrict__ linW, const float* __restrict__ linb,
                                 float* __restrict__ out, int N) {
    int g = blockIdx.x;
    int lo = 0, hi = N;
    while (lo < hi) { int m = (lo + hi) >> 1; if (batch[m] < g) lo = m + 1; else hi = m; }
    int lo2 = lo, hi2 = N;
    while (lo2 < hi2) { int m = (lo2 + hi2) >> 1; if (batch[m] < g + 1) lo2 = m + 1; else hi2 = m; }
    int n0 = lo, n1 = lo2;
    int c  = threadIdx.x & 63;
    int nl = threadIdx.x >> 6;
    float acc = 0.f;
    for (int n = n0 + nl; n < n1; n += 4)
        acc += x[(size_t)n * CH + c];
    __shared__ float lds[4][64];
    lds[nl][c] = acc;
    __syncthreads();
    __shared__ float pooled[64];
    if (threadIdx.x < 64) {
        float cnt = (float)max(n1 - n0, 1);
        pooled[threadIdx.x] = (lds[0][threadIdx.x] + lds[1][threadIdx.x] +
                               lds[2][threadIdx.x] + lds[3][threadIdx.x]) / cnt;
    }
    __syncthreads();
    if (threadIdx.x < 2) {
        int k = threadIdx.x;
        float s = 0.f;
#pragma unroll
        for (int cc = 0; cc < CH; cc++) s += pooled[cc] * linW[cc * 2 + k];
        out[g * 2 + k] = s + linb[k];
    }
}

// ---------------------------------------------------------------------------
extern "C" void kernel_launch(void* const* d_in, const int* in_sizes, int n_in,
                              void* d_out, int out_size, void* d_ws, size_t ws_size,
                              hipStream_t stream) {
    const float* x      = (const float*)d_in[0];
    const int*   ei     = (const int*)d_in[1];
    const int*   batch  = (const int*)d_in[3];
    const float* gamma  = (const float*)d_in[4];
    const float* beta   = (const float*)d_in[5];
    const float* W1     = (const float*)d_in[6];
    const float* a1s    = (const float*)d_in[7];
    const float* a1d    = (const float*)d_in[8];
    const float* b1     = (const float*)d_in[9];
    const float* W2     = (const float*)d_in[10];
    const float* a2s    = (const float*)d_in[11];
    const float* a2d    = (const float*)d_in[12];
    const float* b2     = (const float*)d_in[13];
    const float* W3     = (const float*)d_in[14];
    const float* a3s    = (const float*)d_in[15];
    const float* a3d    = (const float*)d_in[16];
    const float* b3     = (const float*)d_in[17];
    const float* linW   = (const float*)d_in[18];
    const float* linb   = (const float*)d_in[19];
    float* out = (float*)d_out;

    const int N  = in_sizes[0] / 16;
    const int E  = in_sizes[1] / 2;
    const int E2 = E + N;

    // Workspace layout (256B aligned slices)
    char* p = (char*)d_ws;
    size_t off = 0;
    auto alloc = [&](size_t bytes) {
        void* r = p + off;
        off += (bytes + 255) & ~(size_t)255;
        return r;
    };
    unsigned* hbuf   = (unsigned*)alloc((size_t)N * HC * 2);   // bf16 x2 packed
    float* xa        = (float*)alloc((size_t)N * CH * 4);
    float* xb        = (float*)alloc((size_t)N * CH * 4);
    float* asv       = (float*)alloc((size_t)N * HEADS * 4);
    float* adv       = (float*)alloc((size_t)N * HEADS * 4);
    float* stats     = (float*)alloc(64 * 4);
    float* partials  = (float*)alloc((size_t)BNB * 32 * 4);
    float* uv        = (float*)alloc(2304 * 4);
    int*   rowptr    = (int*)alloc((size_t)(N + 1) * 4);
    int*   cursor    = (int*)alloc((size_t)N * 4);
    int*   counts    = (int*)alloc((size_t)N * 4);
    int*   src_csr   = (int*)alloc((size_t)E2 * 4);
    (void)ws_size;

    const int TB = 256;
    int gE2 = (E2 + TB - 1) / TB;
    int gGm = (N + 31) / 32;               // BM=32
    int gWv = (N * 64 + TB - 1) / TB;      // one wave per node
    int bnChunk = (N + BNB - 1) / BNB;

    const ushort* hb = (const ushort*)hbuf;

    // zero-init count accumulators
    hipMemsetAsync(counts, 0, (size_t)N * 4, stream);

    // D1: BN stats partials || CSR count (independent, merged dispatch)
    stats_count_kernel<<<BNB + gE2, TB, 0, stream>>>(x, partials, N, bnChunk,
                                                     ei, E, E2, counts);
    // D2: uv precompute + BN finalize + CSR scan (merged dispatch)
    uv_scan_kernel<<<5, 1024, 0, stream>>>(W1, a1s, a1d, W2, a2s, a2d, W3, a3s, a3d,
                                           uv, partials, stats, gamma, beta, N, BNB,
                                           counts, rowptr, cursor);
    // D3: scatter into CSR
    scatter_kernel<<<gE2, TB, 0, stream>>>(ei, E, E2, cursor, src_csr);

    // ---- Layer 1 (BN fused into GEMM staging; asv/adv fused epilogue) ----
    gemm_kernel<16><<<gGm, TB, 0, stream>>>(x, W1, hbuf, N, stats + 32, stats + 48,
                                            uv + 0, uv + 128, asv, adv);
    agg_kernel<<<gWv, TB, 0, stream>>>(rowptr, src_csr, asv, adv, hb, b1, xa, N, 1);

    // ---- Layer 2 ----
    gemm_kernel<64><<<gGm, TB, 0, stream>>>(xa, W2, hbuf, N, nullptr, nullptr,
                                            uv + 256, uv + 768, asv, adv);
    agg_kernel<<<gWv, TB, 0, stream>>>(rowptr, src_csr, asv, adv, hb, b2, xb, N, 1);

    // ---- Layer 3 ----
    gemm_kernel<64><<<gGm, TB, 0, stream>>>(xb, W3, hbuf, N, nullptr, nullptr,
                                            uv + 1280, uv + 1792, asv, adv);
    agg_kernel<<<gWv, TB, 0, stream>>>(rowptr, src_csr, asv, adv, hb, b3, xa, N, 0);

    // ---- Fused mean-pool + linear ----
    poolfinal_kernel<<<NGR, TB, 0, stream>>>(xa, batch, linW, linb, out, N);
}